// Round 7
// baseline (154.845 us; speedup 1.0000x reference)
//
#include <hip/hip_runtime.h>
#include <math.h>

#define HH 512
#define PP 256
#define LL 4096
#define NB 8
#define BM 256
#define BN 256
#define BK 64
#define KTILES (HH / BK)

typedef __attribute__((ext_vector_type(4))) float f32x4;
typedef __attribute__((ext_vector_type(8))) __bf16 bf16x8;
typedef __attribute__((ext_vector_type(4))) unsigned short us4;
typedef __attribute__((ext_vector_type(8))) unsigned short us8;

// ws layout:
// [0, 512KB)            M1  (2P x H) bf16  rows 0..255 Re(B_bar), 256..511 Im(B_bar)
// [512KB, 1MB)          C2  (H x 2P) bf16  cols 0..255 2Re(C), 256..511 -2Im(C)
// [1MB, 1MB+2KB)        lam (P x 2) f32
// [2MB, 2MB+32MB)       uT / xsT bf16 (NB, L, 512)
// [2MB+32MB, 2MB+64MB)  Bu bf16 (NB, 2P, L), scanned in place

__device__ __forceinline__ unsigned short f2bf(float x) {
  unsigned int u = __builtin_bit_cast(unsigned int, x);
  return (unsigned short)((u + 0x7fffu + ((u >> 16) & 1u)) >> 16);
}
__device__ __forceinline__ float bf2f(unsigned short h) {
  unsigned int u = ((unsigned int)h) << 16;
  return __builtin_bit_cast(float, u);
}
__device__ __forceinline__ float gelu_exact(float x) {
  return 0.5f * x * (1.0f + erff(x * 0.70710678118654752f));
}
__device__ __forceinline__ void gl_lds16(const void* g, void* l) {
  __builtin_amdgcn_global_load_lds(
      (const __attribute__((address_space(1))) unsigned int*)g,
      (__attribute__((address_space(3))) unsigned int*)l, 16, 0, 0);
}

__global__ __launch_bounds__(256) void precompute_params(
    const float* __restrict__ Lre, const float* __restrict__ Lim,
    const float* __restrict__ Bmat, const float* __restrict__ Cmat,
    const float* __restrict__ logstep,
    unsigned short* __restrict__ M1, unsigned short* __restrict__ C2,
    float* __restrict__ lam)
{
  const int p = blockIdx.x;
  const int t = threadIdx.x;
  const float re = Lre[p], im = Lim[p];
  const float step = expf(logstep[p]);
  const float er  = expf(re * step);
  const float lbr = er * cosf(im * step);
  const float lbi = er * sinf(im * step);
  if (t == 0) { lam[2*p] = lbr; lam[2*p+1] = lbi; }
  const float den = re*re + im*im;
  const float nr = lbr - 1.0f, ni = lbi;
  const float gr = (nr*re + ni*im) / den;
  const float gi = (ni*re - nr*im) / den;
  for (int h = t; h < HH; h += 256) {
    const float br = Bmat[(p*HH + h)*2 + 0];
    const float bi = Bmat[(p*HH + h)*2 + 1];
    M1[p*HH + h]        = f2bf(gr*br - gi*bi);   // Re(B_bar)
    M1[(PP+p)*HH + h]   = f2bf(gr*bi + gi*br);   // Im(B_bar)
    const float cr = Cmat[(h*PP + p)*2 + 0];
    const float ci = Cmat[(h*PP + p)*2 + 1];
    C2[h*(2*PP) + p]      = f2bf( 2.0f * cr);
    C2[h*(2*PP) + PP + p] = f2bf(-2.0f * ci);
  }
}

// transpose+convert: in (b, 512, 4096) f32 -> out (b, 4096, 512) bf16
__global__ __launch_bounds__(256) void t_f32_bf16(
    const float* __restrict__ in, unsigned short* __restrict__ outT)
{
  const int b  = blockIdx.z;
  const int l0 = blockIdx.x * 64;
  const int r0 = blockIdx.y * 64;
  const int tid = threadIdx.x;
  __shared__ unsigned short T[64][68];
  const int rr = tid >> 4;
  const int lc = (tid & 15) * 4;
  const float* ib = in + (size_t)b * HH * LL;
#pragma unroll
  for (int i = 0; i < 4; ++i) {
    const float4 v = *(const float4*)(ib + (size_t)(r0 + rr + i*16) * LL + l0 + lc);
    T[lc+0][rr + i*16] = f2bf(v.x);
    T[lc+1][rr + i*16] = f2bf(v.y);
    T[lc+2][rr + i*16] = f2bf(v.z);
    T[lc+3][rr + i*16] = f2bf(v.w);
  }
  __syncthreads();
  unsigned short* ob = outT + (size_t)b * LL * HH;
#pragma unroll
  for (int i = 0; i < 4; ++i) {
    const int l  = (tid >> 4) + i*16;
    const int r4 = (tid & 15) * 4;
    us4 v = *(const us4*)&T[l][r4];
    *(us4*)(ob + (size_t)(l0 + l) * HH + r0 + r4) = v;
  }
}

// transpose: in (b, 512, 4096) bf16 -> out (b, 4096, 512) bf16
__global__ __launch_bounds__(256) void t_bf16_bf16(
    const unsigned short* __restrict__ in, unsigned short* __restrict__ outT)
{
  const int b  = blockIdx.z;
  const int l0 = blockIdx.x * 64;
  const int r0 = blockIdx.y * 64;
  const int tid = threadIdx.x;
  __shared__ unsigned short T[64][68];
  const int rr = tid >> 4;
  const int lc = (tid & 15) * 4;
  const unsigned short* ib = in + (size_t)b * HH * LL;
#pragma unroll
  for (int i = 0; i < 4; ++i) {
    const us4 v = *(const us4*)(ib + (size_t)(r0 + rr + i*16) * LL + l0 + lc);
    T[lc+0][rr + i*16] = v[0];
    T[lc+1][rr + i*16] = v[1];
    T[lc+2][rr + i*16] = v[2];
    T[lc+3][rr + i*16] = v[3];
  }
  __syncthreads();
  unsigned short* ob = outT + (size_t)b * LL * HH;
#pragma unroll
  for (int i = 0; i < 4; ++i) {
    const int l  = (tid >> 4) + i*16;
    const int r4 = (tid & 15) * 4;
    us4 v = *(const us4*)&T[l][r4];
    *(us4*)(ob + (size_t)(l0 + l) * HH + r0 + r4) = v;
  }
}

// Counted-vmcnt pipelined GEMM: C[b](512 x 4096) = A(512x512) x BT[b]^T.
// 256x256 tile, BK=64, 8 waves (2M x 4N), 512 threads, 1 block/CU (grid 256).
// LDS: 2 dbuf x {A,B} x 2 halves x [128][64] bf16 = 128 KiB.
// Per tile t: issue 8 gl_lds for tile t+1 -> s_waitcnt vmcnt(8) (tile-t
// slices landed; t+1's 8 loads stay IN FLIGHT across both barriers) ->
// s_barrier -> 4 quadrant phases (ds_read + 16 MFMA each, setprio-wrapped,
// no intra-tile barriers) -> s_barrier (WAR guard for next stage).
// Both-sides XOR swizzle (R4-verified, 0 conflicts): 8x16B slots/row,
// LDS[row][s] holds source slot s^(row&7); read slot (kk*4+lg)^(lr&7).
template<bool EPI>
__global__ __launch_bounds__(512, 2) void s5_gemm_8ph(
    const unsigned short* __restrict__ A,
    const unsigned short* __restrict__ BT,
    void* __restrict__ Cout,
    const float* __restrict__ Dv,
    const float* __restrict__ Ug)
{
  // XCD-aware bijective swizzle (nwg = 256, %8==0)
  const int nbx = LL / BN;              // 16
  const int nby = HH / BM;              // 2
  const int nwg = nbx * nby * NB;       // 256
  const int hw  = blockIdx.x + nbx * (blockIdx.y + nby * blockIdx.z);
  const int bid = (hw & 7) * (nwg >> 3) + (hw >> 3);
  const int bx = bid % nbx;
  const int by = (bid / nbx) % nby;
  const int b  = bid / (nbx * nby);

  const int n0 = bx * BN;
  const int m0 = by * BM;
  const int tid  = threadIdx.x;
  const int lane = tid & 63;
  const int w    = tid >> 6;           // 0..7
  const int lr = lane & 15, lg = lane >> 4;
  const int wm = w >> 2;               // 0..1
  const int wn = w & 3;                // 0..3

  __shared__ __align__(16) unsigned short As[2][2][128 * BK];  // [dbuf][half][row][k]
  __shared__ __align__(16) unsigned short Bs[2][2][128 * BK];

  const unsigned short* Bb = BT + (size_t)b * LL * HH;

  f32x4 acc[8][4];
#pragma unroll
  for (int i = 0; i < 8; ++i)
#pragma unroll
    for (int j = 0; j < 4; ++j) acc[i][j] = f32x4{0.0f, 0.0f, 0.0f, 0.0f};

  const int swz0 = ((0 * 4 + lg) ^ (lr & 7)) * 8;
  const int swz1 = ((1 * 4 + lg) ^ (lr & 7)) * 8;

  // per half: 1024 16B chunks (128 rows x 8 slots); 512 thr x 2 chunks
#define STAGE(t1)                                                              \
  {                                                                            \
    const int k0  = (t1) * BK;                                                 \
    const int sel = (t1) & 1;                                                  \
    _Pragma("unroll")                                                          \
    for (int i = 0; i < 2; ++i) {                                              \
      const int c   = i * 512 + tid;                                           \
      const int row = c >> 3;                                                  \
      const int ks  = (c & 7) ^ (row & 7);                                     \
      gl_lds16(A  + (size_t)(m0 +       row) * HH + k0 + ks * 8, &As[sel][0][c * 8]); \
      gl_lds16(A  + (size_t)(m0 + 128 + row) * HH + k0 + ks * 8, &As[sel][1][c * 8]); \
      gl_lds16(Bb + (size_t)(n0 +       row) * HH + k0 + ks * 8, &Bs[sel][0][c * 8]); \
      gl_lds16(Bb + (size_t)(n0 + 128 + row) * HH + k0 + ks * 8, &Bs[sel][1][c * 8]); \
    }                                                                          \
  }

  STAGE(0);

  const int nb = (wn & 1) * 64;   // wave's n-offset within its B-half

  for (int t = 0; t < KTILES; ++t) {
    const int d = t & 1;
    if (t + 1 < KTILES) {
      STAGE(t + 1);
      asm volatile("s_waitcnt vmcnt(8)" ::: "memory");
    } else {
      asm volatile("s_waitcnt vmcnt(0)" ::: "memory");
    }
    __builtin_amdgcn_sched_barrier(0);
    __builtin_amdgcn_s_barrier();   // all waves' tile-t slices in LDS

    const unsigned short* Ah = &As[d][wm][0];
    const unsigned short* Bh = &Bs[d][wn >> 1][0];

#pragma unroll
    for (int qm = 0; qm < 2; ++qm) {
      bf16x8 aF[4][2];
#pragma unroll
      for (int i = 0; i < 4; ++i) {
        const int ra = (qm * 64 + i * 16 + lr) * BK;
        aF[i][0] = *(const bf16x8*)&Ah[ra + swz0];
        aF[i][1] = *(const bf16x8*)&Ah[ra + swz1];
      }
#pragma unroll
      for (int qn = 0; qn < 2; ++qn) {
        bf16x8 bF[2][2];
#pragma unroll
        for (int j = 0; j < 2; ++j) {
          const int rb = (nb + qn * 32 + j * 16 + lr) * BK;
          bF[j][0] = *(const bf16x8*)&Bh[rb + swz0];
          bF[j][1] = *(const bf16x8*)&Bh[rb + swz1];
        }
        __builtin_amdgcn_s_setprio(1);
#pragma unroll
        for (int i = 0; i < 4; ++i)
#pragma unroll
          for (int j = 0; j < 2; ++j) {
            acc[qm*4+i][qn*2+j] = __builtin_amdgcn_mfma_f32_16x16x32_bf16(
                aF[i][0], bF[j][0], acc[qm*4+i][qn*2+j], 0, 0, 0);
            acc[qm*4+i][qn*2+j] = __builtin_amdgcn_mfma_f32_16x16x32_bf16(
                aF[i][1], bF[j][1], acc[qm*4+i][qn*2+j], 0, 0, 0);
          }
        __builtin_amdgcn_s_setprio(0);
      }
    }
    __builtin_amdgcn_s_barrier();   // readers of buf d done before next STAGE into d
  }
#undef STAGE

  if (!EPI) {
    unsigned short* C = (unsigned short*)Cout + (size_t)b * HH * LL;
#pragma unroll
    for (int fm = 0; fm < 8; ++fm)
#pragma unroll
      for (int r = 0; r < 4; ++r) {
        const int row = m0 + wm * 128 + fm * 16 + lg * 4 + r;
#pragma unroll
        for (int fn = 0; fn < 4; ++fn) {
          const int col = n0 + wn * 64 + fn * 16 + lr;
          C[(size_t)row * LL + col] = f2bf(acc[fm][fn][r]);
        }
      }
  } else {
    float* C = (float*)Cout + (size_t)b * HH * LL;
    const float* Ub = Ug + (size_t)b * HH * LL;
#pragma unroll
    for (int fm = 0; fm < 8; ++fm)
#pragma unroll
      for (int r = 0; r < 4; ++r) {
        const int row = m0 + wm * 128 + fm * 16 + lg * 4 + r;
        const float dv = Dv[row];
#pragma unroll
        for (int fn = 0; fn < 4; ++fn) {
          const int col = n0 + wn * 64 + fn * 16 + lr;
          const float y = fmaf(dv, Ub[(size_t)row * LL + col], acc[fm][fn][r]);
          C[(size_t)row * LL + col] = gelu_exact(y);
        }
      }
  }
}

// chunked parallel scan per (b,p): x_l = lam*x_{l-1} + Bu_l (complex), bf16 I/O in place
__global__ __launch_bounds__(256) void s5_scan(
    unsigned short* __restrict__ Bu, const float* __restrict__ lam)
{
  const int p = blockIdx.x;
  const int b = blockIdx.y;
  const int t = threadIdx.x;
  unsigned short* rowr = Bu + ((size_t)b*2*PP + p)      * LL;
  unsigned short* rowi = Bu + ((size_t)b*2*PP + PP + p) * LL;

  const float lre = lam[2*p], lim = lam[2*p+1];

  float br[16], bi[16];
  {
    us8 v0 = *(const us8*)&rowr[t*16];
    us8 v1 = *(const us8*)&rowr[t*16 + 8];
    us8 w0 = *(const us8*)&rowi[t*16];
    us8 w1 = *(const us8*)&rowi[t*16 + 8];
#pragma unroll
    for (int j = 0; j < 8; ++j) {
      br[j] = bf2f(v0[j]); br[8+j] = bf2f(v1[j]);
      bi[j] = bf2f(w0[j]); bi[8+j] = bf2f(w1[j]);
    }
  }

  float xr = 0.0f, xi = 0.0f;
#pragma unroll
  for (int j = 0; j < 16; ++j) {
    const float nr = fmaf(lre, xr, fmaf(-lim, xi, br[j]));
    const float ni = fmaf(lre, xi, fmaf( lim, xr, bi[j]));
    xr = nr; xi = ni;
  }

  float mre = lre, mim = lim;
#pragma unroll
  for (int s = 0; s < 4; ++s) {
    const float nr2 = mre*mre - mim*mim;
    mim = 2.0f*mre*mim; mre = nr2;
  }

  __shared__ float sre[256], sim[256];
  float tre = xr, tim = xi;
  sre[t] = tre; sim[t] = tim;
  __syncthreads();
  for (int o = 1; o < 256; o <<= 1) {
    float pr = 0.0f, pi = 0.0f;
    if (t >= o) { pr = sre[t-o]; pi = sim[t-o]; }
    __syncthreads();
    if (t >= o) {
      tre += mre*pr - mim*pi;
      tim += mre*pi + mim*pr;
      sre[t] = tre; sim[t] = tim;
    }
    __syncthreads();
    const float nr2 = mre*mre - mim*mim;
    mim = 2.0f*mre*mim; mre = nr2;
  }

  float cr = 0.0f, ci = 0.0f;
  if (t > 0) { cr = sre[t-1]; ci = sim[t-1]; }

  xr = cr; xi = ci;
  us8 o0, o1, o2, o3;
#pragma unroll
  for (int j = 0; j < 16; ++j) {
    const float nr = fmaf(lre, xr, fmaf(-lim, xi, br[j]));
    const float ni = fmaf(lre, xi, fmaf( lim, xr, bi[j]));
    xr = nr; xi = ni;
    if (j < 8) { o0[j] = f2bf(xr); o2[j] = f2bf(xi); }
    else       { o1[j-8] = f2bf(xr); o3[j-8] = f2bf(xi); }
  }
  *(us8*)&rowr[t*16]     = o0;
  *(us8*)&rowr[t*16 + 8] = o1;
  *(us8*)&rowi[t*16]     = o2;
  *(us8*)&rowi[t*16 + 8] = o3;
}

extern "C" void kernel_launch(void* const* d_in, const int* in_sizes, int n_in,
                              void* d_out, int out_size, void* d_ws, size_t ws_size,
                              hipStream_t stream) {
  (void)in_sizes; (void)n_in; (void)out_size; (void)ws_size;
  const float* in_seq = (const float*)d_in[0];
  const float* Lre    = (const float*)d_in[1];
  const float* Lim    = (const float*)d_in[2];
  const float* Bm     = (const float*)d_in[3];
  const float* Cm     = (const float*)d_in[4];
  const float* Dv     = (const float*)d_in[5];
  const float* ls     = (const float*)d_in[6];
  float* out = (float*)d_out;

  char* ws = (char*)d_ws;
  unsigned short* M1  = (unsigned short*)(ws);
  unsigned short* C2  = (unsigned short*)(ws + (512u << 10));
  float*          lam = (float*)(ws + (1u << 20));
  unsigned short* uT  = (unsigned short*)(ws + (2u << 20));                // 32 MiB, reused as xsT
  unsigned short* Bu  = (unsigned short*)(ws + (2u << 20) + (32u << 20)); // 32 MiB

  precompute_params<<<dim3(PP), dim3(256), 0, stream>>>(Lre, Lim, Bm, Cm, ls, M1, C2, lam);

  t_f32_bf16<<<dim3(LL/64, HH/64, NB), dim3(256), 0, stream>>>(in_seq, uT);

  dim3 gg(LL/BN, HH/BM, NB);   // 16 x 2 x 8 = 256 blocks
  s5_gemm_8ph<false><<<gg, dim3(512), 0, stream>>>(M1, uT, Bu, nullptr, nullptr);

  s5_scan<<<dim3(PP, NB), dim3(256), 0, stream>>>(Bu, lam);

  t_bf16_bf16<<<dim3(LL/64, HH/64, NB), dim3(256), 0, stream>>>(Bu, uT);

  s5_gemm_8ph<true><<<gg, dim3(512), 0, stream>>>(C2, uT, out, Dv, in_seq);
}

// Round 8
// 103.927 us; speedup vs baseline: 1.4899x; 1.4899x over previous
//
#include <hip/hip_runtime.h>
#include <math.h>

#define HH 512
#define PP 256
#define LL 4096
#define NB 8
#define BM 128
#define BN 128
#define BK 32
#define KTILES (HH / BK)

typedef __attribute__((ext_vector_type(4))) float f32x4;
typedef __attribute__((ext_vector_type(8))) __bf16 bf16x8;
typedef __attribute__((ext_vector_type(4))) unsigned short us4;
typedef __attribute__((ext_vector_type(8))) unsigned short us8;

// ws layout:
// [0, 512KB)      M1  (2P x H) bf16  rows 0..255 Re(B_bar), 256..511 Im(B_bar)
// [512KB, 1MB)    C2  (H x 2P) bf16  cols 0..255 2Re(C), 256..511 -2Im(C)
// [1MB, 1MB+2KB)  lam (P x 2) f32
// [2MB, 2MB+32MB) Bu bf16 (NB, 2P, L), scanned in place -> xs

__device__ __forceinline__ unsigned short f2bf(float x) {
  unsigned int u = __builtin_bit_cast(unsigned int, x);
  return (unsigned short)((u + 0x7fffu + ((u >> 16) & 1u)) >> 16);
}
__device__ __forceinline__ float bf2f(unsigned short h) {
  unsigned int u = ((unsigned int)h) << 16;
  return __builtin_bit_cast(float, u);
}
__device__ __forceinline__ float gelu_exact(float x) {
  return 0.5f * x * (1.0f + erff(x * 0.70710678118654752f));
}
__device__ __forceinline__ void gl_lds16(const void* g, void* l) {
  __builtin_amdgcn_global_load_lds(
      (const __attribute__((address_space(1))) unsigned int*)g,
      (__attribute__((address_space(3))) unsigned int*)l, 16, 0, 0);
}

__global__ __launch_bounds__(256) void precompute_params(
    const float* __restrict__ Lre, const float* __restrict__ Lim,
    const float* __restrict__ Bmat, const float* __restrict__ Cmat,
    const float* __restrict__ logstep,
    unsigned short* __restrict__ M1, unsigned short* __restrict__ C2,
    float* __restrict__ lam)
{
  const int p = blockIdx.x;
  const int t = threadIdx.x;
  const float re = Lre[p], im = Lim[p];
  const float step = expf(logstep[p]);
  const float er  = expf(re * step);
  const float lbr = er * cosf(im * step);
  const float lbi = er * sinf(im * step);
  if (t == 0) { lam[2*p] = lbr; lam[2*p+1] = lbi; }
  const float den = re*re + im*im;
  const float nr = lbr - 1.0f, ni = lbi;
  const float gr = (nr*re + ni*im) / den;
  const float gi = (ni*re - nr*im) / den;
  for (int h = t; h < HH; h += 256) {
    const float br = Bmat[(p*HH + h)*2 + 0];
    const float bi = Bmat[(p*HH + h)*2 + 1];
    M1[p*HH + h]        = f2bf(gr*br - gi*bi);   // Re(B_bar)
    M1[(PP+p)*HH + h]   = f2bf(gr*bi + gi*br);   // Im(B_bar)
    const float cr = Cmat[(h*PP + p)*2 + 0];
    const float ci = Cmat[(h*PP + p)*2 + 1];
    C2[h*(2*PP) + p]      = f2bf( 2.0f * cr);
    C2[h*(2*PP) + PP + p] = f2bf(-2.0f * ci);
  }
}

// Fused NN-GEMM: C[b](512 x 4096) = A(512x512, k-contig bf16) x Bsrc[b](512k x 4096n)
// BK=32, 32 KiB LDS/block -> 4 blocks/CU (16 waves/CU).
// R6 structure with T4 counted-vmcnt: raw s_barrier, top-of-iter vmcnt(6)
// (retires only tile-t's 2 A-gl_lds; tile-t+1's 4 B_LOAD + 2 gl_lds stay in
// flight across both barriers), lgkmcnt(0) before closing barrier.
// Swizzle (both-sides involution): row r, 4 slots of 16B (8 elems);
// stored slot s holds source k-oct s ^ g(r), g(r) = (r>>2)&3.
template<bool SRCF32, bool EPI>
__global__ __launch_bounds__(256, 4) void s5_gemm_fused(
    const unsigned short* __restrict__ A,
    const void* __restrict__ Bsrc,
    void* __restrict__ Cout,
    const float* __restrict__ Dv,
    const float* __restrict__ Ug)
{
  // XCD-aware bijective swizzle of flattened block id (nwg = 1024, %8==0)
  const int nbx = LL / BN;              // 32
  const int nby = HH / BM;              // 4
  const int nwg = nbx * nby * NB;       // 1024
  const int hw  = blockIdx.x + nbx * (blockIdx.y + nby * blockIdx.z);
  const int bid = (hw & 7) * (nwg >> 3) + (hw >> 3);
  const int bx = bid % nbx;
  const int by = (bid / nbx) % nby;
  const int b  = bid / (nbx * nby);

  const int n0 = bx * BN;
  const int m0 = by * BM;
  const int tid  = threadIdx.x;
  const int lane = tid & 63;
  const int w    = tid >> 6;
  const int lr = lane & 15, lg = lane >> 4;
  const int wm = (w >> 1) * 64, wn = (w & 1) * 64;

  __shared__ unsigned short As[2][BM * BK];   // 8 KiB x2
  __shared__ unsigned short Bs[2][BN * BK];   // 8 KiB x2

  f32x4 acc[4][4];
#pragma unroll
  for (int i = 0; i < 4; ++i)
#pragma unroll
    for (int j = 0; j < 4; ++j) acc[i][j] = f32x4{0.0f, 0.0f, 0.0f, 0.0f};

  // fragment read offset (elems): slot = lg ^ g(row), g(row) = (lr>>2)&3
  const int swz = (lg ^ ((lr >> 2) & 3)) * 8;

  // B staging decomposition: nq = n-quad (4 n's), ko = k-quad group (4 k's)
  const int nq = tid & 31;   // n2 = nq*4 + j
  const int ko = tid >> 5;   // k rows ko*4 .. ko*4+3 ; k-oct = ko>>1, half = ko&1

  const float*          BsF = (const float*)Bsrc          + (size_t)b * HH * LL;
  const unsigned short* BsH = (const unsigned short*)Bsrc + (size_t)b * HH * LL;

  f32x4 bv[4];  // G1: f32 source regs
  us4   bh[4];  // G2: bf16 source regs

  // A staging: c in [0,512), row = c>>2, slot = c&3,
  // source k-oct = (c&3) ^ g(row) = (c&3) ^ ((c>>4)&3)
#define STAGE_A(k0, sel)                                                       \
  {                                                                            \
    _Pragma("unroll")                                                          \
    for (int i = 0; i < 2; ++i) {                                              \
      const int c   = i * 256 + tid;                                           \
      const int row = c >> 2;                                                  \
      const int ks  = (c & 3) ^ ((c >> 4) & 3);                                \
      gl_lds16(A + (size_t)(m0 + row) * HH + (k0) + ks * 8, &As[sel][c * 8]);  \
    }                                                                          \
  }

#define B_LOAD(k0)                                                             \
  {                                                                            \
    _Pragma("unroll")                                                          \
    for (int r = 0; r < 4; ++r) {                                              \
      if (SRCF32)                                                              \
        bv[r] = *(const f32x4*)(BsF + (size_t)((k0) + ko * 4 + r) * LL + n0 + nq * 4); \
      else                                                                     \
        bh[r] = *(const us4*)(BsH + (size_t)((k0) + ko * 4 + r) * LL + n0 + nq * 4);   \
    }                                                                          \
  }

  // B write: thread's 4 k's form half (ko&1) of k-oct (ko>>1);
  // stored slot = (ko>>1) ^ g(n2), elem off = n2*BK + slot*8 + (ko&1)*4
#define B_WRITE(sel)                                                           \
  {                                                                            \
    _Pragma("unroll")                                                          \
    for (int j = 0; j < 4; ++j) {                                              \
      const int n2 = nq * 4 + j;                                               \
      us4 wv;                                                                  \
      _Pragma("unroll")                                                        \
      for (int r = 0; r < 4; ++r)                                              \
        wv[r] = SRCF32 ? f2bf(bv[r][j]) : bh[r][j];                            \
      const int slot = (ko >> 1) ^ ((n2 >> 2) & 3);                            \
      *(us4*)&Bs[sel][n2 * BK + slot * 8 + (ko & 1) * 4] = wv;                 \
    }                                                                          \
  }

  // prologue: stage tile 0, full drain once
  B_LOAD(0);     // issue B loads FIRST (FIFO: A-lds newest)
  STAGE_A(0, 0);
  B_WRITE(0);
  __syncthreads();

  for (int t = 0; t < KTILES; ++t) {
    const int cur = t & 1;
    const bool more = (t + 1 < KTILES);
    if (more) {
      B_LOAD((t + 1) * BK);                       // 4 VMEM (issue early)
      if (cur) STAGE_A((t + 1) * BK, 0) else STAGE_A((t + 1) * BK, 1);  // 2 VMEM
      // retire only tile-t's A-lds (the 2 oldest); leave this iter's 6 in flight
      asm volatile("s_waitcnt vmcnt(6)" ::: "memory");
    } else {
      asm volatile("s_waitcnt vmcnt(0)" ::: "memory");
    }
    __builtin_amdgcn_sched_barrier(0);
    __builtin_amdgcn_s_barrier();                 // tile-t A in LDS for all waves
    __builtin_amdgcn_sched_barrier(0);

    bf16x8 aF[4], bF[4];
#pragma unroll
    for (int f = 0; f < 4; ++f) {
      aF[f] = *(const bf16x8*)&As[cur][(wm + f * 16 + lr) * BK + swz];
      bF[f] = *(const bf16x8*)&Bs[cur][(wn + f * 16 + lr) * BK + swz];
    }
#pragma unroll
    for (int fm = 0; fm < 4; ++fm)
#pragma unroll
      for (int fn = 0; fn < 4; ++fn)
        acc[fm][fn] = __builtin_amdgcn_mfma_f32_16x16x32_bf16(
            aF[fm], bF[fn], acc[fm][fn], 0, 0, 0);
    if (more) {
      if (cur) B_WRITE(0) else B_WRITE(1);        // write late (compiler waits B regs only)
    }
    asm volatile("s_waitcnt lgkmcnt(0)" ::: "memory");  // my ds_writes visible
    __builtin_amdgcn_sched_barrier(0);
    __builtin_amdgcn_s_barrier();                 // WAR guard for next stage
    __builtin_amdgcn_sched_barrier(0);
  }
#undef STAGE_A
#undef B_LOAD
#undef B_WRITE

  if (!EPI) {
    unsigned short* C = (unsigned short*)Cout + (size_t)b * HH * LL;
#pragma unroll
    for (int fm = 0; fm < 4; ++fm)
#pragma unroll
      for (int r = 0; r < 4; ++r) {
        const int row = m0 + wm + fm*16 + lg*4 + r;
#pragma unroll
        for (int fn = 0; fn < 4; ++fn) {
          const int col = n0 + wn + fn*16 + lr;
          C[(size_t)row * LL + col] = f2bf(acc[fm][fn][r]);
        }
      }
  } else {
    float* C = (float*)Cout + (size_t)b * HH * LL;
    const float* Ub = Ug + (size_t)b * HH * LL;
#pragma unroll
    for (int fm = 0; fm < 4; ++fm)
#pragma unroll
      for (int r = 0; r < 4; ++r) {
        const int row = m0 + wm + fm*16 + lg*4 + r;
        const float dv = Dv[row];
#pragma unroll
        for (int fn = 0; fn < 4; ++fn) {
          const int col = n0 + wn + fn*16 + lr;
          const float y = fmaf(dv, Ub[(size_t)row * LL + col], acc[fm][fn][r]);
          C[(size_t)row * LL + col] = gelu_exact(y);
        }
      }
  }
}

// chunked parallel scan per (b,p): x_l = lam*x_{l-1} + Bu_l (complex), bf16 I/O in place
__global__ __launch_bounds__(256) void s5_scan(
    unsigned short* __restrict__ Bu, const float* __restrict__ lam)
{
  const int p = blockIdx.x;
  const int b = blockIdx.y;
  const int t = threadIdx.x;
  unsigned short* rowr = Bu + ((size_t)b*2*PP + p)      * LL;
  unsigned short* rowi = Bu + ((size_t)b*2*PP + PP + p) * LL;

  const float lre = lam[2*p], lim = lam[2*p+1];

  float br[16], bi[16];
  {
    us8 v0 = *(const us8*)&rowr[t*16];
    us8 v1 = *(const us8*)&rowr[t*16 + 8];
    us8 w0 = *(const us8*)&rowi[t*16];
    us8 w1 = *(const us8*)&rowi[t*16 + 8];
#pragma unroll
    for (int j = 0; j < 8; ++j) {
      br[j] = bf2f(v0[j]); br[8+j] = bf2f(v1[j]);
      bi[j] = bf2f(w0[j]); bi[8+j] = bf2f(w1[j]);
    }
  }

  float xr = 0.0f, xi = 0.0f;
#pragma unroll
  for (int j = 0; j < 16; ++j) {
    const float nr = fmaf(lre, xr, fmaf(-lim, xi, br[j]));
    const float ni = fmaf(lre, xi, fmaf( lim, xr, bi[j]));
    xr = nr; xi = ni;
  }

  float mre = lre, mim = lim;
#pragma unroll
  for (int s = 0; s < 4; ++s) {
    const float nr2 = mre*mre - mim*mim;
    mim = 2.0f*mre*mim; mre = nr2;
  }

  __shared__ float sre[256], sim[256];
  float tre = xr, tim = xi;
  sre[t] = tre; sim[t] = tim;
  __syncthreads();
  for (int o = 1; o < 256; o <<= 1) {
    float pr = 0.0f, pi = 0.0f;
    if (t >= o) { pr = sre[t-o]; pi = sim[t-o]; }
    __syncthreads();
    if (t >= o) {
      tre += mre*pr - mim*pi;
      tim += mre*pi + mim*pr;
      sre[t] = tre; sim[t] = tim;
    }
    __syncthreads();
    const float nr2 = mre*mre - mim*mim;
    mim = 2.0f*mre*mim; mre = nr2;
  }

  float cr = 0.0f, ci = 0.0f;
  if (t > 0) { cr = sre[t-1]; ci = sim[t-1]; }

  xr = cr; xi = ci;
  us8 o0, o1, o2, o3;
#pragma unroll
  for (int j = 0; j < 16; ++j) {
    const float nr = fmaf(lre, xr, fmaf(-lim, xi, br[j]));
    const float ni = fmaf(lre, xi, fmaf( lim, xr, bi[j]));
    xr = nr; xi = ni;
    if (j < 8) { o0[j] = f2bf(xr); o2[j] = f2bf(xi); }
    else       { o1[j-8] = f2bf(xr); o3[j-8] = f2bf(xi); }
  }
  *(us8*)&rowr[t*16]     = o0;
  *(us8*)&rowr[t*16 + 8] = o1;
  *(us8*)&rowi[t*16]     = o2;
  *(us8*)&rowi[t*16 + 8] = o3;
}

extern "C" void kernel_launch(void* const* d_in, const int* in_sizes, int n_in,
                              void* d_out, int out_size, void* d_ws, size_t ws_size,
                              hipStream_t stream) {
  (void)in_sizes; (void)n_in; (void)out_size; (void)ws_size;
  const float* in_seq = (const float*)d_in[0];
  const float* Lre    = (const float*)d_in[1];
  const float* Lim    = (const float*)d_in[2];
  const float* Bm     = (const float*)d_in[3];
  const float* Cm     = (const float*)d_in[4];
  const float* Dv     = (const float*)d_in[5];
  const float* ls     = (const float*)d_in[6];
  float* out = (float*)d_out;

  char* ws = (char*)d_ws;
  unsigned short* M1  = (unsigned short*)(ws);
  unsigned short* C2  = (unsigned short*)(ws + (512u << 10));
  float*          lam = (float*)(ws + (1u << 20));
  unsigned short* Bu  = (unsigned short*)(ws + (2u << 20));   // 32 MiB

  precompute_params<<<dim3(PP), dim3(256), 0, stream>>>(Lre, Lim, Bm, Cm, ls, M1, C2, lam);

  dim3 gg(LL/BN, HH/BM, NB);
  // G1: Bu = M1 x u   (u f32, K-strided -> fused transpose staging)
  s5_gemm_fused<true, false><<<gg, dim3(256), 0, stream>>>(M1, in_seq, Bu, nullptr, nullptr);

  s5_scan<<<dim3(PP, NB), dim3(256), 0, stream>>>(Bu, lam);

  // G2: out = gelu(C2 x xs + D*u)   (xs bf16 in Bu layout)
  s5_gemm_fused<false, true><<<gg, dim3(256), 0, stream>>>(C2, Bu, out, Dv, in_seq);
}